// Round 8
// baseline (697.310 us; speedup 1.0000x reference)
//
#include <hip/hip_runtime.h>
#include <hip/hip_bf16.h>
#include <stdint.h>

#define B_ 256
#define T_ 512
#define V_ 30000
#define E_ 256
#define H_ 32

__device__ __forceinline__ float sigmoidf_fast(float x) {
    return 1.0f / (1.0f + __expf(-x));
}
__device__ __forceinline__ float tanhf_fast(float x) {
    return 1.0f - 2.0f / (1.0f + __expf(2.0f * x));
}

// ---------------------------------------------------------------------------
// GEMM: Out[M,192] = A[M,K] @ Wcat[192,K]^T + bias   (unchanged)
// ---------------------------------------------------------------------------
#define GEMM_MT 64
#define GEMM_KC 32
#define GEMM_PA 68
#define GEMM_PB 196

__global__ __launch_bounds__(256) void gemm_gates(
    const float* __restrict__ A, int M, int K,
    const float* __restrict__ Wf, const float* __restrict__ Wb,
    const float* __restrict__ bihf, const float* __restrict__ bhhf,
    const float* __restrict__ bihb, const float* __restrict__ bhhb,
    float* __restrict__ Out)
{
    __shared__ float As[GEMM_KC][GEMM_PA];
    __shared__ float Bs[GEMM_KC][GEMM_PB];

    const int tid = threadIdx.x;
    const int mbase = blockIdx.x * GEMM_MT;
    const int mg = tid >> 5, ng = tid & 31;
    const int m_off = mg * 8, n_off = ng * 6;

    float acc[8][6];
    #pragma unroll
    for (int r = 0; r < 8; ++r)
        #pragma unroll
        for (int c = 0; c < 6; ++c) acc[r][c] = 0.f;

    for (int kc = 0; kc < K; kc += GEMM_KC) {
        #pragma unroll
        for (int i = 0; i < 2; ++i) {
            int fi = tid + 256 * i;
            int row = fi >> 3, cf = fi & 7;
            int m = mbase + row;
            float4 v = make_float4(0.f, 0.f, 0.f, 0.f);
            if (m < M) v = *(const float4*)&A[(size_t)m * K + kc + cf * 4];
            As[cf * 4 + 0][row] = v.x; As[cf * 4 + 1][row] = v.y;
            As[cf * 4 + 2][row] = v.z; As[cf * 4 + 3][row] = v.w;
        }
        #pragma unroll
        for (int i = 0; i < 6; ++i) {
            int fi = tid + 256 * i;
            int g = fi >> 3, cf = fi & 7;
            const float* Wsel = (g < 96) ? (Wf + (size_t)g * K)
                                         : (Wb + (size_t)(g - 96) * K);
            float4 v = *(const float4*)&Wsel[kc + cf * 4];
            Bs[cf * 4 + 0][g] = v.x; Bs[cf * 4 + 1][g] = v.y;
            Bs[cf * 4 + 2][g] = v.z; Bs[cf * 4 + 3][g] = v.w;
        }
        __syncthreads();
        #pragma unroll
        for (int k = 0; k < GEMM_KC; ++k) {
            float a[8], bb[6];
            *(float4*)&a[0] = *(const float4*)&As[k][m_off];
            *(float4*)&a[4] = *(const float4*)&As[k][m_off + 4];
            *(float2*)&bb[0] = *(const float2*)&Bs[k][n_off];
            *(float2*)&bb[2] = *(const float2*)&Bs[k][n_off + 2];
            *(float2*)&bb[4] = *(const float2*)&Bs[k][n_off + 4];
            #pragma unroll
            for (int r = 0; r < 8; ++r)
                #pragma unroll
                for (int c = 0; c < 6; ++c)
                    acc[r][c] = fmaf(a[r], bb[c], acc[r][c]);
        }
        __syncthreads();
    }

    float bias[6];
    #pragma unroll
    for (int c = 0; c < 6; ++c) {
        int g = n_off + c;
        int g96 = (g < 96) ? g : g - 96;
        const float* bih = (g < 96) ? bihf : bihb;
        const float* bhh = (g < 96) ? bhhf : bhhb;
        bias[c] = bih[g96] + ((g96 < 64) ? bhh[g96] : 0.f);
    }
    #pragma unroll
    for (int r = 0; r < 8; ++r) {
        int m = mbase + m_off + r;
        if (m < M) {
            float* op = &Out[(size_t)m * 192 + n_off];
            #pragma unroll
            for (int c = 0; c < 6; ++c) op[c] = acc[r][c] + bias[c];
        }
    }
}

// ---------------------------------------------------------------------------
// GRU scan, 2 sequences per wave. Lanes 0-31 = forward dir, lanes 32-63 =
// backward dir of the SAME batch element (identical instruction stream, no
// divergence). Each lane owns unit j=l&31 and computes all 3 gates.
//
// h broadcast: 32 __shfl(h, (l&32)+k) issued as ONE BLOCK into hk[] (they
// are independent -> pipeline in the DS pipe, one graduated lgkm wait),
// then a separate block of 96 scalar v_fma. sched_barrier(0) between the
// blocks prevents the R6 failure mode (per-shfl interleave = 32 serialized
// LDS round-trips/step, VALUBusy 10%).
//
// Loads: R5's proven two-bank 4-step-chunk prefetch, per-lane dir. int4
// components picked via .x/.y/.z/.w ternaries with static u — NEVER via
// pointer casts (R7: taking addresses pushed banks into LDS scratch,
// 9.6M bank conflicts).
// ---------------------------------------------------------------------------
__device__ __forceinline__ int comp4(int4 v, int u) {
    return u == 0 ? v.x : u == 1 ? v.y : u == 2 ? v.z : v.w;
}

template <int USE_IDS>
__global__ __launch_bounds__(64)
__attribute__((amdgpu_waves_per_eu(1, 1)))
void gru_scan(
    const float* __restrict__ gi,     // [rows,192]: G0 (gather) or gi1 (direct)
    const int* __restrict__ ids,
    const int* __restrict__ mask,
    const float* __restrict__ Whh_f, const float* __restrict__ Whh_b,
    const float* __restrict__ bhh_f, const float* __restrict__ bhh_b,
    float* __restrict__ out_seq,      // [B,T,64] or nullptr
    float* __restrict__ out_fin)      // [B,64]   or nullptr
{
    const int l = threadIdx.x;
    const int j = l & 31;
    const int dir = l >> 5;           // 0 = fwd (lanes 0-31), 1 = bwd (32-63)
    const int sh = l & 32;            // shuffle base of own half
    const int b = blockIdx.x;
    const int bT = b * T_;

    const float* Whh = dir ? Whh_b : Whh_f;
    const float* bhh = dir ? bhh_b : bhh_f;

    // per-lane weight rows (r=j, z=32+j, n=64+j)
    float wR[32], wZ[32], wN[32];
    #pragma unroll
    for (int q = 0; q < 8; ++q) {
        float4 a = *(const float4*)&Whh[j * 32 + q * 4];
        wR[q * 4 + 0] = a.x; wR[q * 4 + 1] = a.y;
        wR[q * 4 + 2] = a.z; wR[q * 4 + 3] = a.w;
        float4 zq = *(const float4*)&Whh[(32 + j) * 32 + q * 4];
        wZ[q * 4 + 0] = zq.x; wZ[q * 4 + 1] = zq.y;
        wZ[q * 4 + 2] = zq.z; wZ[q * 4 + 3] = zq.w;
        float4 nq = *(const float4*)&Whh[(64 + j) * 32 + q * 4];
        wN[q * 4 + 0] = nq.x; wN[q * 4 + 1] = nq.y;
        wN[q * 4 + 2] = nq.z; wN[q * 4 + 3] = nq.w;
    }
    const float bn = bhh[64 + j];

    const int offR = dir * 96 + j;
    const int offZ = dir * 96 + 32 + j;
    const int offN = dir * 96 + 64 + j;

    // int4 word base for chunk c, clamped; per-lane direction
    auto wbase = [&](int c) {
        c = (c < 127) ? c : 127;
        return dir ? (bT + 508 - 4 * c) : (bT + 4 * c);
    };
    // component for body u of a chunk, honoring per-lane direction
    auto compd = [&](int4 v, int u) {
        return dir ? comp4(v, 3 - u) : comp4(v, u);
    };

    // ---- prologue ----
    int4 ids_use = make_int4(0,0,0,0), ids_pf = ids_use, ids_mid = ids_use,
         ids_in = ids_use;
    if (USE_IDS) {
        ids_use = *(const int4*)&ids[wbase(0)];
        ids_pf  = *(const int4*)&ids[wbase(1)];
        ids_mid = *(const int4*)&ids[wbase(2)];
    }
    int4 mask_use = *(const int4*)&mask[wbase(0)];
    int4 mask_mid = *(const int4*)&mask[wbase(1)];
    int4 mask_in  = make_int4(0,0,0,0);

    float gR[2][4], gZ[2][4], gN[2][4];
    #pragma unroll
    for (int u = 0; u < 4; ++u) {
        const int row = USE_IDS ? compd(ids_use, u)
                                : (bT + (dir ? (511 - u) : u));
        const float* gp = gi + (size_t)row * 192;
        gR[0][u] = gp[offR];
        gZ[0][u] = gp[offZ];
        gN[0][u] = gp[offN];
    }

    float h = 0.f;

    for (int c2 = 0; c2 < 64; ++c2) {
        #pragma unroll
        for (int p = 0; p < 2; ++p) {
            const int c = 2 * c2 + p;
            if (USE_IDS) ids_in = *(const int4*)&ids[wbase(c + 3)];
            mask_in = *(const int4*)&mask[wbase(c + 2)];
            const int cN = (c + 1 < 128) ? (c + 1) : 127;

            #pragma unroll
            for (int u = 0; u < 4; ++u) {
                // --- gi prefetch for chunk c+1, body u, into bank p^1
                const int rowN = USE_IDS
                    ? compd(ids_pf, u)
                    : (bT + (dir ? (511 - 4 * cN - u) : (4 * cN + u)));
                const float* gpN = gi + (size_t)rowN * 192;
                gR[p ^ 1][u] = gpN[offR];
                gZ[p ^ 1][u] = gpN[offZ];
                gN[p ^ 1][u] = gpN[offN];

                const int m = compd(mask_use, u);

                // --- broadcast block: 32 independent shfls, then barrier
                float hk[32];
                #pragma unroll
                for (int k = 0; k < 32; ++k)
                    hk[k] = __shfl(h, sh + k, 64);
                __builtin_amdgcn_sched_barrier(0);

                // --- matvec block: 96 scalar FMAs, 4-way split chains
                float aR[4] = {0.f, 0.f, 0.f, 0.f};
                float aZ[4] = {0.f, 0.f, 0.f, 0.f};
                float aN[4] = {0.f, 0.f, 0.f, 0.f};
                #pragma unroll
                for (int k = 0; k < 32; ++k) {
                    aR[k & 3] = fmaf(wR[k], hk[k], aR[k & 3]);
                    aZ[k & 3] = fmaf(wZ[k], hk[k], aZ[k & 3]);
                    aN[k & 3] = fmaf(wN[k], hk[k], aN[k & 3]);
                }
                const float dR = (aR[0] + aR[1]) + (aR[2] + aR[3]);
                const float dZ = (aZ[0] + aZ[1]) + (aZ[2] + aZ[3]);
                const float dN = (aN[0] + aN[1]) + (aN[2] + aN[3]);

                const float r  = sigmoidf_fast(gR[p][u] + dR);
                const float z  = sigmoidf_fast(gZ[p][u] + dZ);
                const float hn = bn + dN;
                const float n  = tanhf_fast(gN[p][u] + r * hn);
                const float hnew = n + z * (h - n);     // (1-z)n + z h
                h = m ? hnew : h;                       // packed-seq freeze

                if (out_seq != nullptr) {
                    const int t = dir ? (511 - 4 * c - u) : (4 * c + u);
                    out_seq[(size_t)(bT + t) * 64 + dir * 32 + j] = h;
                }
            }
            // rotate chunk-granular regs (never touches gi banks)
            mask_use = mask_mid; mask_mid = mask_in;
            if (USE_IDS) { ids_pf = ids_mid; ids_mid = ids_in; }
        }
    }

    if (out_fin != nullptr)
        out_fin[b * 64 + dir * 32 + j] = h;
}

// ---------------------------------------------------------------------------
// Head: out[b,o] = hfin[b,:] . Wout[o,:] + bout[o]
// ---------------------------------------------------------------------------
__global__ void head_kernel(const float* __restrict__ hfin,
                            const float* __restrict__ Wout,
                            const float* __restrict__ bout,
                            float* __restrict__ out)
{
    int idx = blockIdx.x * blockDim.x + threadIdx.x;
    if (idx >= B_ * 6) return;
    int b = idx / 6, o = idx % 6;
    float acc = bout[o];
    const float* hp = hfin + b * 64;
    const float* wp = Wout + o * 64;
    #pragma unroll
    for (int k = 0; k < 64; ++k) acc = fmaf(hp[k], wp[k], acc);
    out[idx] = acc;
}

// ---------------------------------------------------------------------------
extern "C" void kernel_launch(void* const* d_in, const int* in_sizes, int n_in,
                              void* d_out, int out_size, void* d_ws, size_t ws_size,
                              hipStream_t stream)
{
    const int*   ids   = (const int*)d_in[0];
    const int*   mask  = (const int*)d_in[1];
    const float* embed = (const float*)d_in[2];
    const float* Wih0f = (const float*)d_in[3];
    const float* Whh0f = (const float*)d_in[4];
    const float* bih0f = (const float*)d_in[5];
    const float* bhh0f = (const float*)d_in[6];
    const float* Wih0b = (const float*)d_in[7];
    const float* Whh0b = (const float*)d_in[8];
    const float* bih0b = (const float*)d_in[9];
    const float* bhh0b = (const float*)d_in[10];
    const float* Wih1f = (const float*)d_in[11];
    const float* Whh1f = (const float*)d_in[12];
    const float* bih1f = (const float*)d_in[13];
    const float* bhh1f = (const float*)d_in[14];
    const float* Wih1b = (const float*)d_in[15];
    const float* Whh1b = (const float*)d_in[16];
    const float* bih1b = (const float*)d_in[17];
    const float* bhh1b = (const float*)d_in[18];
    const float* Wout  = (const float*)d_in[19];
    const float* bout  = (const float*)d_in[20];

    // workspace layout (floats):
    //   gbuf : G0 [V,192] (K1,K2) then gi1 [B*T,192] (K3,K4)
    //   x1   : [B,T,64]
    //   hfin : [B,64]
    float* ws   = (float*)d_ws;
    float* gbuf = ws;
    float* x1   = ws + (size_t)B_ * T_ * 192;
    float* hfin = x1 + (size_t)B_ * T_ * 64;

    // K1: vocab-factored layer-0 input gates  G0 = embed @ Wcat0^T + bias
    gemm_gates<<<(V_ + GEMM_MT - 1) / GEMM_MT, 256, 0, stream>>>(
        embed, V_, E_, Wih0f, Wih0b, bih0f, bhh0f, bih0b, bhh0b, gbuf);

    // K2: layer-0 bidirectional scan (gathers G0[id]), writes x1
    gru_scan<1><<<B_, 64, 0, stream>>>(
        gbuf, ids, mask, Whh0f, Whh0b, bhh0f, bhh0b, x1, nullptr);

    // K3: layer-1 input gates  gi1 = x1 @ Wcat1^T + bias  (overwrites dead G0)
    gemm_gates<<<(B_ * T_) / GEMM_MT, 256, 0, stream>>>(
        x1, B_ * T_, 64, Wih1f, Wih1b, bih1f, bhh1f, bih1b, bhh1b, gbuf);

    // K4: layer-1 scan, final hiddens only
    gru_scan<0><<<B_, 64, 0, stream>>>(
        gbuf, nullptr, mask, Whh1f, Whh1b, bhh1f, bhh1b, nullptr, hfin);

    // K5: output head
    head_kernel<<<(B_ * 6 + 255) / 256, 256, 0, stream>>>(hfin, Wout, bout,
                                                          (float*)d_out);
}

// Round 9
// 667.734 us; speedup vs baseline: 1.0443x; 1.0443x over previous
//
#include <hip/hip_runtime.h>
#include <hip/hip_bf16.h>
#include <stdint.h>

#define B_ 256
#define T_ 512
#define V_ 30000
#define E_ 256
#define H_ 32

typedef float v2f __attribute__((ext_vector_type(2)));

__device__ __forceinline__ float sigmoidf_fast(float x) {
    return 1.0f / (1.0f + __expf(-x));
}
__device__ __forceinline__ float tanhf_fast(float x) {
    return 1.0f - 2.0f / (1.0f + __expf(2.0f * x));
}
__device__ __forceinline__ uint32_t rlu(float v, int lane) {
    return (uint32_t)__builtin_amdgcn_readlane(__float_as_int(v), lane);
}
// packed fp32 FMA: acc.{lo,hi} += w.{lo,hi} * h{k,k+1}  (h-pair in SGPR pair)
__device__ __forceinline__ void pk_fma(v2f& acc, v2f w, uint64_t hh) {
    asm("v_pk_fma_f32 %0, %1, %2, %0" : "+v"(acc) : "v"(w), "s"(hh));
}

// ---------------------------------------------------------------------------
// GEMM: Out[M,192] = A[M,K] @ Wcat[192,K]^T + bias   (unchanged)
// ---------------------------------------------------------------------------
#define GEMM_MT 64
#define GEMM_KC 32
#define GEMM_PA 68
#define GEMM_PB 196

__global__ __launch_bounds__(256) void gemm_gates(
    const float* __restrict__ A, int M, int K,
    const float* __restrict__ Wf, const float* __restrict__ Wb,
    const float* __restrict__ bihf, const float* __restrict__ bhhf,
    const float* __restrict__ bihb, const float* __restrict__ bhhb,
    float* __restrict__ Out)
{
    __shared__ float As[GEMM_KC][GEMM_PA];
    __shared__ float Bs[GEMM_KC][GEMM_PB];

    const int tid = threadIdx.x;
    const int mbase = blockIdx.x * GEMM_MT;
    const int mg = tid >> 5, ng = tid & 31;
    const int m_off = mg * 8, n_off = ng * 6;

    float acc[8][6];
    #pragma unroll
    for (int r = 0; r < 8; ++r)
        #pragma unroll
        for (int c = 0; c < 6; ++c) acc[r][c] = 0.f;

    for (int kc = 0; kc < K; kc += GEMM_KC) {
        #pragma unroll
        for (int i = 0; i < 2; ++i) {
            int fi = tid + 256 * i;
            int row = fi >> 3, cf = fi & 7;
            int m = mbase + row;
            float4 v = make_float4(0.f, 0.f, 0.f, 0.f);
            if (m < M) v = *(const float4*)&A[(size_t)m * K + kc + cf * 4];
            As[cf * 4 + 0][row] = v.x; As[cf * 4 + 1][row] = v.y;
            As[cf * 4 + 2][row] = v.z; As[cf * 4 + 3][row] = v.w;
        }
        #pragma unroll
        for (int i = 0; i < 6; ++i) {
            int fi = tid + 256 * i;
            int g = fi >> 3, cf = fi & 7;
            const float* Wsel = (g < 96) ? (Wf + (size_t)g * K)
                                         : (Wb + (size_t)(g - 96) * K);
            float4 v = *(const float4*)&Wsel[kc + cf * 4];
            Bs[cf * 4 + 0][g] = v.x; Bs[cf * 4 + 1][g] = v.y;
            Bs[cf * 4 + 2][g] = v.z; Bs[cf * 4 + 3][g] = v.w;
        }
        __syncthreads();
        #pragma unroll
        for (int k = 0; k < GEMM_KC; ++k) {
            float a[8], bb[6];
            *(float4*)&a[0] = *(const float4*)&As[k][m_off];
            *(float4*)&a[4] = *(const float4*)&As[k][m_off + 4];
            *(float2*)&bb[0] = *(const float2*)&Bs[k][n_off];
            *(float2*)&bb[2] = *(const float2*)&Bs[k][n_off + 2];
            *(float2*)&bb[4] = *(const float2*)&Bs[k][n_off + 4];
            #pragma unroll
            for (int r = 0; r < 8; ++r)
                #pragma unroll
                for (int c = 0; c < 6; ++c)
                    acc[r][c] = fmaf(a[r], bb[c], acc[r][c]);
        }
        __syncthreads();
    }

    float bias[6];
    #pragma unroll
    for (int c = 0; c < 6; ++c) {
        int g = n_off + c;
        int g96 = (g < 96) ? g : g - 96;
        const float* bih = (g < 96) ? bihf : bihb;
        const float* bhh = (g < 96) ? bhhf : bhhb;
        bias[c] = bih[g96] + ((g96 < 64) ? bhh[g96] : 0.f);
    }
    #pragma unroll
    for (int r = 0; r < 8; ++r) {
        int m = mbase + m_off + r;
        if (m < M) {
            float* op = &Out[(size_t)m * 192 + n_off];
            #pragma unroll
            for (int c = 0; c < 6; ++c) op[c] = acc[r][c] + bias[c];
        }
    }
}

// ---------------------------------------------------------------------------
// GRU scan, LDS-staged. One wave per (batch, direction); h[j] in lane j,
// upper half redundant. Compute = R5's readlane + v_pk_fma (absmax 0.0).
//
// R9 memory structure: time in 16 chunks of 32 steps, double-buffered in LDS
// (sg[2][32][96]). Per 8-step group: issue 16 global loads for the NEXT
// chunk -> run 8 compute bodies (~2400 cyc, covers HBM latency ~900) ->
// ds_write staged values (their vmcnt waits land ~2400 cyc after issue =
// ~free, once per 8 steps). Bodies read 3 gi floats + mask from LDS at body
// top: lgkmcnt-precise, ~120 cyc latency hidden behind the ~300 cyc matvec.
// ids/mask are wave-uniform; lanes 0-7 pull them through LDS once per chunk.
// Evidence: FETCH ~21.7 GB/dispatch at ~100 MB useful = every per-step gi
// load was an HBM-latency compulsory miss; register-bank prefetch never hid
// it (R2-R7).
// ---------------------------------------------------------------------------
template <int USE_IDS>
__global__ __launch_bounds__(64)
__attribute__((amdgpu_waves_per_eu(1, 1)))
void gru_scan(
    const float* __restrict__ gi,     // [rows,192]: G0 (gather) or gi1 (direct)
    const int* __restrict__ ids,
    const int* __restrict__ mask,
    const float* __restrict__ Whh_f, const float* __restrict__ Whh_b,
    const float* __restrict__ bhh_f, const float* __restrict__ bhh_b,
    float* __restrict__ out_seq,      // [B,T,64] or nullptr
    float* __restrict__ out_fin)      // [B,64]   or nullptr
{
    __shared__ float sg[2][32 * 96];  // staged gi: slot s: [0..63]=R|Z, [64..95]=N
    __shared__ int   sid[2][32];      // ids of a chunk (array order = memory order)
    __shared__ int   smk[2][32];      // mask of a chunk

    const int l = threadIdx.x;
    const int j = l & 31;
    const bool lower = l < 32;
    const int dir = blockIdx.x & 1;
    const int b = blockIdx.x >> 1;
    const int bT = b * T_;

    const float* Whh = dir ? Whh_b : Whh_f;
    const float* bhh = dir ? bhh_b : bhh_f;

    // per-lane weight rows (r=j, z=32+j, n=64+j) as fp32 pairs
    v2f wR[16], wZ[16], wN[16];
    #pragma unroll
    for (int q = 0; q < 16; ++q) {
        wR[q] = *(const v2f*)&Whh[j * 32 + 2 * q];
        wZ[q] = *(const v2f*)&Whh[(32 + j) * 32 + 2 * q];
        wN[q] = *(const v2f*)&Whh[(64 + j) * 32 + 2 * q];
    }
    const float bn = bhh[64 + j];

    // absolute word base of chunk Q's 32 ids/mask words (ascending memory)
    auto wb = [&](int Q) {
        Q = (Q < 15) ? Q : 15;
        return bT + (dir ? (480 - 32 * Q) : (32 * Q));
    };
    // array index within a chunk's 32 words for chunk-local step s
    auto karr = [&](int s) { return dir ? (31 - s) : s; };
    // gi row for chunk C, local step s (non-gather path)
    auto trow = [&](int C, int s) {
        const int i = 32 * C + s;
        return bT + (dir ? (511 - i) : i);
    };

    // ---------------- prologue ----------------
    if (l < 8) {
        if (USE_IDS) {
            *(int4*)&sid[0][4 * l] = *(const int4*)&ids[wb(0) + 4 * l];
            *(int4*)&sid[1][4 * l] = *(const int4*)&ids[wb(1) + 4 * l];
        }
        *(int4*)&smk[0][4 * l] = *(const int4*)&mask[wb(0) + 4 * l];
        *(int4*)&smk[1][4 * l] = *(const int4*)&mask[wb(1) + 4 * l];
    }
    // stage chunk 0 into half 0 (one-time, latency irrelevant)
    for (int s = 0; s < 32; ++s) {
        const int row = USE_IDS ? sid[0][karr(s)] : trow(0, s);
        const float* gp = gi + (size_t)row * 192 + dir * 96;
        const float vA = gp[l];
        sg[0][s * 96 + l] = vA;
        if (lower) sg[0][s * 96 + 64 + j] = gp[64 + j];
    }

    float h = 0.f;

    // ---------------- main: 16 chunk-phases ----------------
    #pragma unroll 1
    for (int cc = 0; cc < 8; ++cc) {
        #pragma unroll
        for (int p = 0; p < 2; ++p) {
            const int C  = 2 * cc + p;     // chunk being computed
            const int hp = p;              // its LDS half (C & 1 == p)
            const int Cs = (C + 1 < 16) ? (C + 1) : 15;   // chunk being staged

            #pragma unroll 1
            for (int g = 0; g < 4; ++g) {
                // ---- stage-load subgroup: next chunk, steps 8g..8g+7 ----
                float vA[8], vB[8];
                #pragma unroll
                for (int s2 = 0; s2 < 8; ++s2) {
                    const int s = 8 * g + s2;
                    const int row = USE_IDS ? sid[hp ^ 1][karr(s)]
                                            : trow(Cs, s);
                    const float* gp = gi + (size_t)row * 192 + dir * 96;
                    vA[s2] = gp[l];
                    vB[s2] = lower ? gp[64 + j] : 0.f;
                }

                // ---- 8 compute bodies of chunk C ----
                #pragma unroll
                for (int s2 = 0; s2 < 8; ++s2) {
                    const int s = 8 * g + s2;
                    // body inputs from LDS (issued early; hidden by matvec)
                    const float rR = sg[hp][s * 96 + j];
                    const float rZ = sg[hp][s * 96 + 32 + j];
                    const float rN = sg[hp][s * 96 + 64 + j];
                    const int   m  = smk[hp][karr(s)];

                    v2f aR = {0.f, 0.f}, aZ = {0.f, 0.f}, aN = {0.f, 0.f};
                    #pragma unroll
                    for (int k = 0; k < 16; ++k) {
                        const uint32_t hlo = rlu(h, 2 * k);
                        const uint32_t hhi = rlu(h, 2 * k + 1);
                        const uint64_t hh = ((uint64_t)hhi << 32) | hlo;
                        pk_fma(aR, wR[k], hh);
                        pk_fma(aZ, wZ[k], hh);
                        pk_fma(aN, wN[k], hh);
                    }
                    const float r  = sigmoidf_fast(rR + aR.x + aR.y);
                    const float z  = sigmoidf_fast(rZ + aZ.x + aZ.y);
                    const float hn = bn + aN.x + aN.y;
                    const float n  = tanhf_fast(rN + r * hn);
                    const float hnew = n + z * (h - n);   // (1-z)n + z h
                    h = m ? hnew : h;                     // packed-seq freeze

                    if (out_seq != nullptr) {
                        const int i = 32 * C + s;
                        const int t = dir ? (511 - i) : i;
                        if (lower)
                            out_seq[(size_t)(bT + t) * 64 + dir * 32 + j] = h;
                    }
                }

                // ---- stage-write subgroup (vmcnt waits ~2400 cyc after issue)
                #pragma unroll
                for (int s2 = 0; s2 < 8; ++s2) {
                    const int s = 8 * g + s2;
                    sg[hp ^ 1][s * 96 + l] = vA[s2];
                    if (lower) sg[hp ^ 1][s * 96 + 64 + j] = vB[s2];
                }
            }

            // ---- end of phase: pull ids/mask of chunk C+2 into bank hp ----
            if (l < 8) {
                if (USE_IDS)
                    *(int4*)&sid[hp][4 * l] = *(const int4*)&ids[wb(C + 2) + 4 * l];
                *(int4*)&smk[hp][4 * l] = *(const int4*)&mask[wb(C + 2) + 4 * l];
            }
        }
    }

    if (out_fin != nullptr && lower)
        out_fin[b * 64 + dir * 32 + j] = h;
}

// ---------------------------------------------------------------------------
// Head: out[b,o] = hfin[b,:] . Wout[o,:] + bout[o]
// ---------------------------------------------------------------------------
__global__ void head_kernel(const float* __restrict__ hfin,
                            const float* __restrict__ Wout,
                            const float* __restrict__ bout,
                            float* __restrict__ out)
{
    int idx = blockIdx.x * blockDim.x + threadIdx.x;
    if (idx >= B_ * 6) return;
    int b = idx / 6, o = idx % 6;
    float acc = bout[o];
    const float* hp = hfin + b * 64;
    const float* wp = Wout + o * 64;
    #pragma unroll
    for (int k = 0; k < 64; ++k) acc = fmaf(hp[k], wp[k], acc);
    out[idx] = acc;
}

// ---------------------------------------------------------------------------
extern "C" void kernel_launch(void* const* d_in, const int* in_sizes, int n_in,
                              void* d_out, int out_size, void* d_ws, size_t ws_size,
                              hipStream_t stream)
{
    const int*   ids   = (const int*)d_in[0];
    const int*   mask  = (const int*)d_in[1];
    const float* embed = (const float*)d_in[2];
    const float* Wih0f = (const float*)d_in[3];
    const float* Whh0f = (const float*)d_in[4];
    const float* bih0f = (const float*)d_in[5];
    const float* bhh0f = (const float*)d_in[6];
    const float* Wih0b = (const float*)d_in[7];
    const float* Whh0b = (const float*)d_in[8];
    const float* bih0b = (const float*)d_in[9];
    const float* bhh0b = (const float*)d_in[10];
    const float* Wih1f = (const float*)d_in[11];
    const float* Whh1f = (const float*)d_in[12];
    const float* bih1f = (const float*)d_in[13];
    const float* bhh1f = (const float*)d_in[14];
    const float* Wih1b = (const float*)d_in[15];
    const float* Whh1b = (const float*)d_in[16];
    const float* bih1b = (const float*)d_in[17];
    const float* bhh1b = (const float*)d_in[18];
    const float* Wout  = (const float*)d_in[19];
    const float* bout  = (const float*)d_in[20];

    // workspace layout (floats):
    //   gbuf : G0 [V,192] (K1,K2) then gi1 [B*T,192] (K3,K4)
    //   x1   : [B,T,64]
    //   hfin : [B,64]
    float* ws   = (float*)d_ws;
    float* gbuf = ws;
    float* x1   = ws + (size_t)B_ * T_ * 192;
    float* hfin = x1 + (size_t)B_ * T_ * 64;

    // K1: vocab-factored layer-0 input gates  G0 = embed @ Wcat0^T + bias
    gemm_gates<<<(V_ + GEMM_MT - 1) / GEMM_MT, 256, 0, stream>>>(
        embed, V_, E_, Wih0f, Wih0b, bih0f, bhh0f, bih0b, bhh0b, gbuf);

    // K2: layer-0 bidirectional scan (gathers G0[id]), writes x1
    gru_scan<1><<<2 * B_, 64, 0, stream>>>(
        gbuf, ids, mask, Whh0f, Whh0b, bhh0f, bhh0b, x1, nullptr);

    // K3: layer-1 input gates  gi1 = x1 @ Wcat1^T + bias  (overwrites dead G0)
    gemm_gates<<<(B_ * T_) / GEMM_MT, 256, 0, stream>>>(
        x1, B_ * T_, 64, Wih1f, Wih1b, bih1f, bhh1f, bih1b, bhh1b, gbuf);

    // K4: layer-1 scan, final hiddens only
    gru_scan<0><<<2 * B_, 64, 0, stream>>>(
        gbuf, nullptr, mask, Whh1f, Whh1b, bhh1f, bhh1b, nullptr, hfin);

    // K5: output head
    head_kernel<<<(B_ * 6 + 255) / 256, 256, 0, stream>>>(hfin, Wout, bout,
                                                          (float*)d_out);
}